// Round 1
// baseline (7421.617 us; speedup 1.0000x reference)
//
#include <hip/hip_runtime.h>
#include <math.h>

#define TR 16

__global__ __launch_bounds__(256) void qnet_fused(
    const float* __restrict__ x,        // [2048,5]
    const float* __restrict__ actions,  // [64,4]
    const float* __restrict__ W1, const float* __restrict__ b1, // [9,128],[128]
    const float* __restrict__ W2, const float* __restrict__ b2, // [128,1024],[1024]
    const float* __restrict__ W3, const float* __restrict__ b3, // [1024,1024],[1024]
    const float* __restrict__ W4, const float* __restrict__ b4, // [1024,128],[128]
    const float* __restrict__ W5, const float* __restrict__ b5, // [128,1],[1]
    float* __restrict__ values)         // [2048*64]
{
    __shared__ float h_small[TR][128];   // h1, later reused for h4
    __shared__ float hA[TR][1024];       // h2
    __shared__ float hB[TR][1024];       // h3

    const int t = threadIdx.x;
    const int p0 = blockIdx.x * TR;

    // ---------- layer 1: h1 = tanh([x|a] @ W1 + b1), d_in = 9 ----------
    for (int i = t; i < TR * 128; i += 256) {
        int r = i >> 7, c = i & 127;
        int p = p0 + r;
        int bidx = p >> 6, aidx = p & 63;
        float acc = b1[c];
        #pragma unroll
        for (int k = 0; k < 5; ++k) acc += x[bidx * 5 + k] * W1[k * 128 + c];
        #pragma unroll
        for (int k = 0; k < 4; ++k) acc += actions[aidx * 4 + k] * W1[(5 + k) * 128 + c];
        h_small[r][c] = tanhf(acc);
    }
    __syncthreads();

    // ---------- layer 2: 128 -> 1024 ----------
    {
        const int c0 = t * 4;
        float4 bias = *(const float4*)&b2[c0];
        float acc[TR][4];
        #pragma unroll
        for (int r = 0; r < TR; ++r) {
            acc[r][0] = bias.x; acc[r][1] = bias.y; acc[r][2] = bias.z; acc[r][3] = bias.w;
        }
        for (int k = 0; k < 128; k += 4) {
            float4 w0 = *(const float4*)&W2[(k + 0) * 1024 + c0];
            float4 w1 = *(const float4*)&W2[(k + 1) * 1024 + c0];
            float4 w2 = *(const float4*)&W2[(k + 2) * 1024 + c0];
            float4 w3 = *(const float4*)&W2[(k + 3) * 1024 + c0];
            #pragma unroll
            for (int r = 0; r < TR; ++r) {
                float4 hv = *(const float4*)&h_small[r][k];  // broadcast read
                acc[r][0] += hv.x * w0.x + hv.y * w1.x + hv.z * w2.x + hv.w * w3.x;
                acc[r][1] += hv.x * w0.y + hv.y * w1.y + hv.z * w2.y + hv.w * w3.y;
                acc[r][2] += hv.x * w0.z + hv.y * w1.z + hv.z * w2.z + hv.w * w3.z;
                acc[r][3] += hv.x * w0.w + hv.y * w1.w + hv.z * w2.w + hv.w * w3.w;
            }
        }
        #pragma unroll
        for (int r = 0; r < TR; ++r) {
            hA[r][c0 + 0] = tanhf(acc[r][0]);
            hA[r][c0 + 1] = tanhf(acc[r][1]);
            hA[r][c0 + 2] = tanhf(acc[r][2]);
            hA[r][c0 + 3] = tanhf(acc[r][3]);
        }
    }
    __syncthreads();

    // ---------- layer 3: 1024 -> 1024 ----------
    {
        const int c0 = t * 4;
        float4 bias = *(const float4*)&b3[c0];
        float acc[TR][4];
        #pragma unroll
        for (int r = 0; r < TR; ++r) {
            acc[r][0] = bias.x; acc[r][1] = bias.y; acc[r][2] = bias.z; acc[r][3] = bias.w;
        }
        for (int k = 0; k < 1024; k += 4) {
            float4 w0 = *(const float4*)&W3[(k + 0) * 1024 + c0];
            float4 w1 = *(const float4*)&W3[(k + 1) * 1024 + c0];
            float4 w2 = *(const float4*)&W3[(k + 2) * 1024 + c0];
            float4 w3 = *(const float4*)&W3[(k + 3) * 1024 + c0];
            #pragma unroll
            for (int r = 0; r < TR; ++r) {
                float4 hv = *(const float4*)&hA[r][k];  // broadcast read
                acc[r][0] += hv.x * w0.x + hv.y * w1.x + hv.z * w2.x + hv.w * w3.x;
                acc[r][1] += hv.x * w0.y + hv.y * w1.y + hv.z * w2.y + hv.w * w3.y;
                acc[r][2] += hv.x * w0.z + hv.y * w1.z + hv.z * w2.z + hv.w * w3.z;
                acc[r][3] += hv.x * w0.w + hv.y * w1.w + hv.z * w2.w + hv.w * w3.w;
            }
        }
        #pragma unroll
        for (int r = 0; r < TR; ++r) {
            hB[r][c0 + 0] = tanhf(acc[r][0]);
            hB[r][c0 + 1] = tanhf(acc[r][1]);
            hB[r][c0 + 2] = tanhf(acc[r][2]);
            hB[r][c0 + 3] = tanhf(acc[r][3]);
        }
    }
    __syncthreads();

    // ---------- layer 4: 1024 -> 128 ----------
    {
        const int c = t & 127;
        const int rh = t >> 7;        // 0 or 1 -> rows rh*8 .. rh*8+7
        float acc[8];
        float bias = b4[c];
        #pragma unroll
        for (int r = 0; r < 8; ++r) acc[r] = bias;
        for (int k = 0; k < 1024; k += 4) {
            float w0 = W4[(k + 0) * 128 + c];
            float w1 = W4[(k + 1) * 128 + c];
            float w2 = W4[(k + 2) * 128 + c];
            float w3 = W4[(k + 3) * 128 + c];
            #pragma unroll
            for (int r = 0; r < 8; ++r) {
                float4 hv = *(const float4*)&hB[rh * 8 + r][k];  // broadcast within wave
                acc[r] += hv.x * w0 + hv.y * w1 + hv.z * w2 + hv.w * w3;
            }
        }
        #pragma unroll
        for (int r = 0; r < 8; ++r) h_small[rh * 8 + r][c] = tanhf(acc[r]);
    }
    __syncthreads();

    // ---------- layer 5: 128 -> 1, write values ----------
    if (t < TR) {
        float acc = b5[0];
        for (int k = 0; k < 128; k += 4) {
            float4 hv = *(const float4*)&h_small[t][k];
            float4 wv = *(const float4*)&W5[k];
            acc += hv.x * wv.x + hv.y * wv.y + hv.z * wv.z + hv.w * wv.w;
        }
        values[p0 + t] = acc;
    }
}

__global__ __launch_bounds__(256) void argmax_gather(
    const float* __restrict__ values,   // [2048,64]
    const float* __restrict__ actions,  // [64,4]
    float* __restrict__ out_actions)    // [2048,4]
{
    const int wave = threadIdx.x >> 6;
    const int lane = threadIdx.x & 63;
    const int state = blockIdx.x * (blockDim.x >> 6) + wave;
    float v = values[state * 64 + lane];
    int idx = lane;
    #pragma unroll
    for (int off = 32; off; off >>= 1) {
        float ov = __shfl_down(v, off);
        int oi = __shfl_down(idx, off);
        if (ov > v || (ov == v && oi < idx)) { v = ov; idx = oi; }
    }
    idx = __shfl(idx, 0);  // first-max index, numpy semantics
    if (lane < 4) out_actions[state * 4 + lane] = actions[idx * 4 + lane];
}

extern "C" void kernel_launch(void* const* d_in, const int* in_sizes, int n_in,
                              void* d_out, int out_size, void* d_ws, size_t ws_size,
                              hipStream_t stream) {
    const float* x       = (const float*)d_in[0];
    const float* actions = (const float*)d_in[1];
    const float* W1 = (const float*)d_in[2];  const float* b1 = (const float*)d_in[3];
    const float* W2 = (const float*)d_in[4];  const float* b2 = (const float*)d_in[5];
    const float* W3 = (const float*)d_in[6];  const float* b3 = (const float*)d_in[7];
    const float* W4 = (const float*)d_in[8];  const float* b4 = (const float*)d_in[9];
    const float* W5 = (const float*)d_in[10]; const float* b5 = (const float*)d_in[11];

    float* out_actions = (float*)d_out;             // [2048,4]
    float* values      = (float*)d_out + 2048 * 4;  // [2048,64]

    const int R = 2048 * 64;
    qnet_fused<<<R / TR, 256, 0, stream>>>(x, actions, W1, b1, W2, b2, W3, b3,
                                           W4, b4, W5, b5, values);
    argmax_gather<<<2048 / 4, 256, 0, stream>>>(values, actions, out_actions);
}

// Round 2
// 2508.779 us; speedup vs baseline: 2.9583x; 2.9583x over previous
//
#include <hip/hip_runtime.h>
#include <math.h>

// ---------------- common helpers ----------------

typedef short bf16x8 __attribute__((ext_vector_type(8)));
typedef float f32x4 __attribute__((ext_vector_type(4)));

__device__ __host__ inline unsigned short f2bf(float f) {
    union { float f; unsigned u; } v; v.f = f;
    unsigned r = v.u + 0x7fff + ((v.u >> 16) & 1);   // round-to-nearest-even
    return (unsigned short)(r >> 16);
}
__device__ inline float bf2f(unsigned short b) {
    union { unsigned u; float f; } v; v.u = ((unsigned)b) << 16;
    return v.f;
}
__device__ inline float fast_tanh(float x) {
    // tanh(x) = 1 - 2/(exp(2x)+1); exact at +-inf, ~1e-6 abs err
    float e = __expf(2.0f * x);
    return 1.0f - 2.0f / (e + 1.0f);
}

#define DELTA 0.0625f

// ---------------- weight packing (fp32 -> bf16 MFMA B-fragment layout) ----------------
// For mfma_f32_16x16x32_bf16: B-fragment lane l holds col n=(l&15), k = 8*(l>>4)+e.
// packed[blob][lane][e], blob = (n>>4)*(K/32) + (k>>5); each blob = 64 lanes * 8 bf16 = 1KB.
__global__ __launch_bounds__(256) void pack_w(const float* __restrict__ src,
                                              unsigned short* __restrict__ dst,
                                              int K, int N) {
    int i = blockIdx.x * 256 + threadIdx.x;
    if (i >= K * N) return;
    int k = i / N, n = i % N;
    int blob = (n >> 4) * (K >> 5) + (k >> 5);
    int lane = (n & 15) | (((k >> 3) & 3) << 4);
    int e = k & 7;
    dst[(size_t)blob * 512 + lane * 8 + e] = f2bf(src[i]);
}

// ---------------- main fused MFMA kernel ----------------
// Block = one state (64 rows = 64 actions). 512 threads = 8 waves (4 row-tiles x 2 col-groups).
__global__ __launch_bounds__(512, 2) void qnet_mfma(
    const float* __restrict__ x,        // [2048,5]
    const float* __restrict__ actions,  // [64,4]
    const float* __restrict__ W1, const float* __restrict__ b1,
    const float* __restrict__ b2, const float* __restrict__ b3,
    const float* __restrict__ b4,
    const float* __restrict__ W5, const float* __restrict__ b5,
    const unsigned short* __restrict__ W2p,   // packed [128,1024]
    const unsigned short* __restrict__ W3p,   // packed [1024,1024]
    const unsigned short* __restrict__ W4p,   // packed [1024,128]
    float* __restrict__ values)               // [2048*64]
{
    __shared__ unsigned short h2[64 * 1024];  // 128 KB, XOR-swizzled rows
    __shared__ unsigned short hc[64 * 128];   // 16 KB: h1, then h3 chunks, then h4

    const int t = threadIdx.x;
    const int lane = t & 63;
    const int wave = t >> 6;     // 0..7
    const int wm = wave >> 1;    // row-tile 0..3 (rows wm*16..)
    const int wn = wave & 1;     // col-group 0..1
    const int p0 = blockIdx.x * 64;
    const int rloc = wm * 16 + (lane & 15);     // A-fragment row
    const int asel = (lane >> 4) * 8;           // A-fragment k sub-offset
    const int rsw = (rloc & 7) << 4;            // swizzle bits for rloc

    // ---- layer 1: h1 = tanh([x|a] @ W1 + b1) ----
    {
        int r = t >> 3;              // 0..63 (= action index)
        int c0 = (t & 7) * 16;
        const float* xs = &x[blockIdx.x * 5];
        const float* as = &actions[r * 4];
        float in[9] = { xs[0], xs[1], xs[2], xs[3], xs[4], as[0], as[1], as[2], as[3] };
        #pragma unroll 4
        for (int j = 0; j < 16; ++j) {
            int c = c0 + j;
            float acc = b1[c];
            #pragma unroll
            for (int k = 0; k < 9; ++k) acc += in[k] * W1[k * 128 + c];
            *(unsigned short*)((char*)hc + r * 256 + (((c * 2) ^ ((r & 7) << 4)))) =
                f2bf(fast_tanh(acc));
        }
    }
    __syncthreads();

    // ---- layer 2: h2 = tanh(h1 @ W2 + b2), 128 -> 1024, 4 col-chunks of 256 ----
    for (int cc = 0; cc < 4; ++cc) {
        f32x4 acc[8];
        #pragma unroll
        for (int f = 0; f < 8; ++f) {
            float bv = b2[cc * 256 + wn * 128 + f * 16 + (lane & 15)];
            acc[f] = (f32x4){ bv, bv, bv, bv };
        }
        #pragma unroll
        for (int ks = 0; ks < 4; ++ks) {
            bf16x8 a = *(const bf16x8*)((const char*)hc + rloc * 256 +
                                        ((((ks * 32 + asel) * 2)) ^ rsw));
            #pragma unroll
            for (int f = 0; f < 8; ++f) {
                int nTile = cc * 16 + wn * 8 + f;
                bf16x8 b = *(const bf16x8*)&W2p[((size_t)(nTile * 4 + ks)) * 512 + lane * 8];
                acc[f] = __builtin_amdgcn_mfma_f32_16x16x32_bf16(a, b, acc[f], 0, 0, 0);
            }
        }
        #pragma unroll
        for (int f = 0; f < 8; ++f) {
            int n = cc * 256 + wn * 128 + f * 16 + (lane & 15);
            #pragma unroll
            for (int rr = 0; rr < 4; ++rr) {
                int m = wm * 16 + (lane >> 4) * 4 + rr;
                *(unsigned short*)((char*)h2 + m * 2048 + (((n * 2) ^ ((m & 7) << 4)))) =
                    f2bf(fast_tanh(acc[f][rr]));
            }
        }
    }
    __syncthreads();

    // ---- layers 3+4 interleaved: h3 chunked [64,128], layer4 K-accumulated ----
    f32x4 acc4[4];
    #pragma unroll
    for (int f = 0; f < 4; ++f) {
        float bv = b4[wn * 64 + f * 16 + (lane & 15)];
        acc4[f] = (f32x4){ bv, bv, bv, bv };
    }

    for (int c = 0; c < 8; ++c) {
        // layer3 chunk: cols [c*128, c*128+128)
        f32x4 acc3[4];
        #pragma unroll
        for (int f = 0; f < 4; ++f) {
            float bv = b3[c * 128 + wn * 64 + f * 16 + (lane & 15)];
            acc3[f] = (f32x4){ bv, bv, bv, bv };
        }
        #pragma unroll 2
        for (int ks = 0; ks < 32; ++ks) {
            bf16x8 a = *(const bf16x8*)((const char*)h2 + rloc * 2048 +
                                        ((((ks * 32 + asel) * 2)) ^ rsw));
            #pragma unroll
            for (int f = 0; f < 4; ++f) {
                int nTile = c * 8 + wn * 4 + f;
                bf16x8 b = *(const bf16x8*)&W3p[((size_t)(nTile * 32 + ks)) * 512 + lane * 8];
                acc3[f] = __builtin_amdgcn_mfma_f32_16x16x32_bf16(a, b, acc3[f], 0, 0, 0);
            }
        }
        __syncthreads();   // previous layer4 reads of hc complete
        #pragma unroll
        for (int f = 0; f < 4; ++f) {
            int nl = wn * 64 + f * 16 + (lane & 15);
            #pragma unroll
            for (int rr = 0; rr < 4; ++rr) {
                int m = wm * 16 + (lane >> 4) * 4 + rr;
                *(unsigned short*)((char*)hc + m * 256 + (((nl * 2) ^ ((m & 7) << 4)))) =
                    f2bf(fast_tanh(acc3[f][rr]));
            }
        }
        __syncthreads();   // hc chunk ready
        // layer4 partial accumulate over this K-chunk
        #pragma unroll
        for (int ks = 0; ks < 4; ++ks) {
            bf16x8 a = *(const bf16x8*)((const char*)hc + rloc * 256 +
                                        ((((ks * 32 + asel) * 2)) ^ rsw));
            #pragma unroll
            for (int f = 0; f < 4; ++f) {
                int nTile = wn * 4 + f;
                bf16x8 b = *(const bf16x8*)&W4p[((size_t)(nTile * 32 + c * 4 + ks)) * 512 + lane * 8];
                acc4[f] = __builtin_amdgcn_mfma_f32_16x16x32_bf16(a, b, acc4[f], 0, 0, 0);
            }
        }
    }
    __syncthreads();   // last layer4 hc reads done

    // ---- h4 = tanh(acc4) -> hc ----
    #pragma unroll
    for (int f = 0; f < 4; ++f) {
        int nl = wn * 64 + f * 16 + (lane & 15);
        #pragma unroll
        for (int rr = 0; rr < 4; ++rr) {
            int m = wm * 16 + (lane >> 4) * 4 + rr;
            *(unsigned short*)((char*)hc + m * 256 + (((nl * 2) ^ ((m & 7) << 4)))) =
                f2bf(fast_tanh(acc4[f][rr]));
        }
    }
    __syncthreads();

    // ---- layer 5: values = h4 @ W5 + b5 ----
    {
        int r = t >> 3, g = t & 7;
        float part = 0.0f;
        #pragma unroll
        for (int j = 0; j < 16; ++j) {
            int cidx = g * 16 + j;
            unsigned short hb = *(const unsigned short*)((const char*)hc + r * 256 +
                                  (((cidx * 2) ^ ((r & 7) << 4))));
            part += bf2f(hb) * W5[cidx];
        }
        part += __shfl_down(part, 4);
        part += __shfl_down(part, 2);
        part += __shfl_down(part, 1);
        if (g == 0) values[p0 + r] = part + b5[0];
    }
}

// ---------------- argmax fixup: exact fp32 recompute for ambiguous rows ----------------
__global__ __launch_bounds__(256) void argmax_fixup(
    const float* __restrict__ values, const float* __restrict__ x,
    const float* __restrict__ actions,
    const float* __restrict__ W1, const float* __restrict__ b1,
    const float* __restrict__ W2, const float* __restrict__ b2,
    const float* __restrict__ W3, const float* __restrict__ b3,
    const float* __restrict__ W4, const float* __restrict__ b4,
    const float* __restrict__ W5, const float* __restrict__ b5,
    float* __restrict__ out_actions)
{
    __shared__ float h1[128], h2f[1024], h3f[1024], h4f[128];
    __shared__ int cand[64];
    __shared__ int ncand;
    __shared__ float bestv;
    __shared__ int besti;

    const int s = blockIdx.x;
    const int t = threadIdx.x;

    if (t < 64) {
        float v = values[s * 64 + t];
        float m = v;
        #pragma unroll
        for (int off = 32; off; off >>= 1) m = fmaxf(m, __shfl_down(m, off));
        m = __shfl(m, 0);
        unsigned long long mask = __ballot(v >= m - DELTA);
        if (t == 0) {
            int n = 0;
            while (mask) { int j = __ffsll(mask) - 1; cand[n++] = j; mask &= mask - 1; }
            ncand = n;
            bestv = -1e30f; besti = -1;
        }
    }
    __syncthreads();

    if (ncand == 1) {
        if (t < 4) out_actions[s * 4 + t] = actions[cand[0] * 4 + t];
        return;
    }

    for (int ci = 0; ci < ncand; ++ci) {
        int aidx = cand[ci];
        if (t < 128) {
            float acc = b1[t];
            #pragma unroll
            for (int k = 0; k < 5; ++k) acc += x[s * 5 + k] * W1[k * 128 + t];
            #pragma unroll
            for (int k = 0; k < 4; ++k) acc += actions[aidx * 4 + k] * W1[(5 + k) * 128 + t];
            h1[t] = tanhf(acc);
        }
        __syncthreads();
        for (int cc = 0; cc < 4; ++cc) {
            int c = t + cc * 256;
            float acc = b2[c];
            for (int k = 0; k < 128; ++k) acc += h1[k] * W2[k * 1024 + c];
            h2f[c] = tanhf(acc);
        }
        __syncthreads();
        for (int cc = 0; cc < 4; ++cc) {
            int c = t + cc * 256;
            float acc = b3[c];
            for (int k = 0; k < 1024; ++k) acc += h2f[k] * W3[k * 1024 + c];
            h3f[c] = tanhf(acc);
        }
        __syncthreads();
        if (t < 128) {
            float acc = b4[t];
            for (int k = 0; k < 1024; ++k) acc += h3f[k] * W4[k * 128 + t];
            h4f[t] = tanhf(acc);
        }
        __syncthreads();
        if (t < 64) {
            float p = h4f[t] * W5[t] + h4f[t + 64] * W5[t + 64];
            #pragma unroll
            for (int off = 32; off; off >>= 1) p += __shfl_down(p, off);
            if (t == 0) {
                float v = p + b5[0];
                if (v > bestv) { bestv = v; besti = aidx; }  // ascending cand order => first-max
            }
        }
        __syncthreads();
    }
    if (t < 4) out_actions[s * 4 + t] = actions[besti * 4 + t];
}

// ---------------- fallback fp32 path (used only if ws too small) ----------------
#define TR 16
__global__ __launch_bounds__(256) void qnet_fused(
    const float* __restrict__ x, const float* __restrict__ actions,
    const float* __restrict__ W1, const float* __restrict__ b1,
    const float* __restrict__ W2, const float* __restrict__ b2,
    const float* __restrict__ W3, const float* __restrict__ b3,
    const float* __restrict__ W4, const float* __restrict__ b4,
    const float* __restrict__ W5, const float* __restrict__ b5,
    float* __restrict__ values)
{
    __shared__ float h_small[TR][128];
    __shared__ float hA[TR][1024];
    __shared__ float hB[TR][1024];
    const int t = threadIdx.x;
    const int p0 = blockIdx.x * TR;
    for (int i = t; i < TR * 128; i += 256) {
        int r = i >> 7, c = i & 127;
        int p = p0 + r;
        int bidx = p >> 6, aidx = p & 63;
        float acc = b1[c];
        for (int k = 0; k < 5; ++k) acc += x[bidx * 5 + k] * W1[k * 128 + c];
        for (int k = 0; k < 4; ++k) acc += actions[aidx * 4 + k] * W1[(5 + k) * 128 + c];
        h_small[r][c] = tanhf(acc);
    }
    __syncthreads();
    {
        const int c0 = t * 4;
        float4 bias = *(const float4*)&b2[c0];
        float acc[TR][4];
        for (int r = 0; r < TR; ++r) { acc[r][0]=bias.x; acc[r][1]=bias.y; acc[r][2]=bias.z; acc[r][3]=bias.w; }
        for (int k = 0; k < 128; k += 4) {
            float4 w0 = *(const float4*)&W2[(k+0)*1024+c0];
            float4 w1 = *(const float4*)&W2[(k+1)*1024+c0];
            float4 w2 = *(const float4*)&W2[(k+2)*1024+c0];
            float4 w3 = *(const float4*)&W2[(k+3)*1024+c0];
            for (int r = 0; r < TR; ++r) {
                float4 hv = *(const float4*)&h_small[r][k];
                acc[r][0] += hv.x*w0.x + hv.y*w1.x + hv.z*w2.x + hv.w*w3.x;
                acc[r][1] += hv.x*w0.y + hv.y*w1.y + hv.z*w2.y + hv.w*w3.y;
                acc[r][2] += hv.x*w0.z + hv.y*w1.z + hv.z*w2.z + hv.w*w3.z;
                acc[r][3] += hv.x*w0.w + hv.y*w1.w + hv.z*w2.w + hv.w*w3.w;
            }
        }
        for (int r = 0; r < TR; ++r) {
            hA[r][c0+0]=tanhf(acc[r][0]); hA[r][c0+1]=tanhf(acc[r][1]);
            hA[r][c0+2]=tanhf(acc[r][2]); hA[r][c0+3]=tanhf(acc[r][3]);
        }
    }
    __syncthreads();
    {
        const int c0 = t * 4;
        float4 bias = *(const float4*)&b3[c0];
        float acc[TR][4];
        for (int r = 0; r < TR; ++r) { acc[r][0]=bias.x; acc[r][1]=bias.y; acc[r][2]=bias.z; acc[r][3]=bias.w; }
        for (int k = 0; k < 1024; k += 4) {
            float4 w0 = *(const float4*)&W3[(k+0)*1024+c0];
            float4 w1 = *(const float4*)&W3[(k+1)*1024+c0];
            float4 w2 = *(const float4*)&W3[(k+2)*1024+c0];
            float4 w3 = *(const float4*)&W3[(k+3)*1024+c0];
            for (int r = 0; r < TR; ++r) {
                float4 hv = *(const float4*)&hA[r][k];
                acc[r][0] += hv.x*w0.x + hv.y*w1.x + hv.z*w2.x + hv.w*w3.x;
                acc[r][1] += hv.x*w0.y + hv.y*w1.y + hv.z*w2.y + hv.w*w3.y;
                acc[r][2] += hv.x*w0.z + hv.y*w1.z + hv.z*w2.z + hv.w*w3.z;
                acc[r][3] += hv.x*w0.w + hv.y*w1.w + hv.z*w2.w + hv.w*w3.w;
            }
        }
        for (int r = 0; r < TR; ++r) {
            hB[r][c0+0]=tanhf(acc[r][0]); hB[r][c0+1]=tanhf(acc[r][1]);
            hB[r][c0+2]=tanhf(acc[r][2]); hB[r][c0+3]=tanhf(acc[r][3]);
        }
    }
    __syncthreads();
    {
        const int c = t & 127;
        const int rh = t >> 7;
        float acc[8];
        float bias = b4[c];
        for (int r = 0; r < 8; ++r) acc[r] = bias;
        for (int k = 0; k < 1024; k += 4) {
            float w0 = W4[(k+0)*128+c], w1 = W4[(k+1)*128+c];
            float w2 = W4[(k+2)*128+c], w3 = W4[(k+3)*128+c];
            for (int r = 0; r < 8; ++r) {
                float4 hv = *(const float4*)&hB[rh*8+r][k];
                acc[r] += hv.x*w0 + hv.y*w1 + hv.z*w2 + hv.w*w3;
            }
        }
        for (int r = 0; r < 8; ++r) h_small[rh*8+r][c] = tanhf(acc[r]);
    }
    __syncthreads();
    if (t < TR) {
        float acc = b5[0];
        for (int k = 0; k < 128; k += 4) {
            float4 hv = *(const float4*)&h_small[t][k];
            float4 wv = *(const float4*)&W5[k];
            acc += hv.x*wv.x + hv.y*wv.y + hv.z*wv.z + hv.w*wv.w;
        }
        values[p0 + t] = acc;
    }
}

__global__ __launch_bounds__(256) void argmax_gather(
    const float* __restrict__ values, const float* __restrict__ actions,
    float* __restrict__ out_actions)
{
    const int wave = threadIdx.x >> 6;
    const int lane = threadIdx.x & 63;
    const int state = blockIdx.x * (blockDim.x >> 6) + wave;
    float v = values[state * 64 + lane];
    int idx = lane;
    for (int off = 32; off; off >>= 1) {
        float ov = __shfl_down(v, off);
        int oi = __shfl_down(idx, off);
        if (ov > v || (ov == v && oi < idx)) { v = ov; idx = oi; }
    }
    idx = __shfl(idx, 0);
    if (lane < 4) out_actions[state * 4 + lane] = actions[idx * 4 + lane];
}

// ---------------- launcher ----------------
extern "C" void kernel_launch(void* const* d_in, const int* in_sizes, int n_in,
                              void* d_out, int out_size, void* d_ws, size_t ws_size,
                              hipStream_t stream) {
    const float* x       = (const float*)d_in[0];
    const float* actions = (const float*)d_in[1];
    const float* W1 = (const float*)d_in[2];  const float* b1 = (const float*)d_in[3];
    const float* W2 = (const float*)d_in[4];  const float* b2 = (const float*)d_in[5];
    const float* W3 = (const float*)d_in[6];  const float* b3 = (const float*)d_in[7];
    const float* W4 = (const float*)d_in[8];  const float* b4 = (const float*)d_in[9];
    const float* W5 = (const float*)d_in[10]; const float* b5 = (const float*)d_in[11];

    float* out_actions = (float*)d_out;              // [2048,4]
    float* values      = (float*)d_out + 2048 * 4;   // [2048,64]

    const size_t nW2 = 128 * 1024, nW3 = 1024 * 1024, nW4 = 1024 * 128;
    const size_t need = (nW2 + nW3 + nW4) * sizeof(unsigned short);

    if (ws_size >= need) {
        unsigned short* W2p = (unsigned short*)d_ws;
        unsigned short* W3p = W2p + nW2;
        unsigned short* W4p = W3p + nW3;
        pack_w<<<(int)((nW2 + 255) / 256), 256, 0, stream>>>(W2, W2p, 128, 1024);
        pack_w<<<(int)((nW3 + 255) / 256), 256, 0, stream>>>(W3, W3p, 1024, 1024);
        pack_w<<<(int)((nW4 + 255) / 256), 256, 0, stream>>>(W4, W4p, 1024, 128);
        qnet_mfma<<<2048, 512, 0, stream>>>(x, actions, W1, b1, b2, b3, b4, W5, b5,
                                            W2p, W3p, W4p, values);
        argmax_fixup<<<2048, 256, 0, stream>>>(values, x, actions,
                                               W1, b1, W2, b2, W3, b3, W4, b4, W5, b5,
                                               out_actions);
    } else {
        qnet_fused<<<2048 * 64 / TR, 256, 0, stream>>>(x, actions, W1, b1, W2, b2, W3, b3,
                                                       W4, b4, W5, b5, values);
        argmax_gather<<<2048 / 4, 256, 0, stream>>>(values, actions, out_actions);
    }
}

// Round 3
// 934.740 us; speedup vs baseline: 7.9398x; 2.6839x over previous
//
#include <hip/hip_runtime.h>
#include <math.h>

// ---------------- common helpers ----------------

typedef short bf16x8 __attribute__((ext_vector_type(8)));
typedef float f32x4 __attribute__((ext_vector_type(4)));
typedef float f32x16 __attribute__((ext_vector_type(16)));

__device__ __host__ inline unsigned short f2bf(float f) {
    union { float f; unsigned u; } v; v.f = f;
    unsigned r = v.u + 0x7fff + ((v.u >> 16) & 1);   // round-to-nearest-even
    return (unsigned short)(r >> 16);
}
__device__ inline float bf2f(unsigned short b) {
    union { unsigned u; float f; } v; v.u = ((unsigned)b) << 16;
    return v.f;
}
__device__ inline float fast_tanh(float x) {
    float e = __expf(2.0f * x);
    return 1.0f - 2.0f / (e + 1.0f);
}

#define DELTA 0.035f
#define WL_CAP 4096

struct WLE { unsigned long long mask; unsigned s; unsigned pad; };

// hc rows are 256 B, h2 rows are 2048 B; (row&15)<<4 is bijective within both.
#define HSWZ(row, b) ((b) ^ (((row) & 15) << 4))

// ---------------- weight packing ----------------
// 16x16x32 B-frag: lane l holds col n=(l&15), k=8*(l>>4)+e (verified in round 2).
__global__ __launch_bounds__(256) void pack_w16(const float* __restrict__ src,
                                                unsigned short* __restrict__ dst,
                                                int K, int N) {
    int i = blockIdx.x * 256 + threadIdx.x;
    if (i >= K * N) return;
    int k = i / N, n = i % N;
    int blob = (n >> 4) * (K >> 5) + (k >> 5);
    int lane = (n & 15) | (((k >> 3) & 3) << 4);
    int e = k & 7;
    dst[(size_t)blob * 512 + lane * 8 + e] = f2bf(src[i]);
}
// 32x32x16 B-frag: lane l holds col n=(l&31), k=8*(l>>5)+e (analogous mapping).
__global__ __launch_bounds__(256) void pack_w32(const float* __restrict__ src,
                                                unsigned short* __restrict__ dst,
                                                int K, int N) {
    int i = blockIdx.x * 256 + threadIdx.x;
    if (i >= K * N) return;
    int k = i / N, n = i % N;
    int blob = (n >> 5) * (K >> 4) + (k >> 4);
    int lane = (n & 31) | (((k >> 3) & 1) << 5);
    int e = k & 7;
    dst[(size_t)blob * 512 + lane * 8 + e] = f2bf(src[i]);
}

// ---------------- main fused MFMA kernel ----------------
__global__ __launch_bounds__(512, 1) void qnet_mfma(
    const float* __restrict__ x, const float* __restrict__ actions,
    const float* __restrict__ W1, const float* __restrict__ b1,
    const float* __restrict__ b2, const float* __restrict__ b3,
    const float* __restrict__ b4,
    const float* __restrict__ W5, const float* __restrict__ b5,
    const unsigned short* __restrict__ W2p,
    const unsigned short* __restrict__ W3p,
    const unsigned short* __restrict__ W4p,
    float* __restrict__ values)
{
    __shared__ unsigned short h2[64 * 1024];  // 128 KB
    __shared__ unsigned short hc[64 * 128];   // 16 KB: h1 -> h3 chunks -> h4

    const int t = threadIdx.x;
    const int lane = t & 63;
    const int wave = t >> 6;
    const int p0 = blockIdx.x * 64;

    // ---- layer 1 ----
    {
        int r = t >> 3;              // action index 0..63
        int c0 = (t & 7) * 16;
        const float* xs = &x[blockIdx.x * 5];
        const float* as = &actions[r * 4];
        float in[9] = { xs[0], xs[1], xs[2], xs[3], xs[4], as[0], as[1], as[2], as[3] };
        #pragma unroll 4
        for (int j = 0; j < 16; ++j) {
            int c = c0 + j;
            float acc = b1[c];
            #pragma unroll
            for (int k = 0; k < 9; ++k) acc += in[k] * W1[k * 128 + c];
            *(unsigned short*)((char*)hc + r * 256 + HSWZ(r, c * 2)) = f2bf(fast_tanh(acc));
        }
    }
    __syncthreads();

    // ---- layer 2: 128 -> 1024 (16x16x32, 4x2 wave grid) ----
    const int wm = wave >> 1, wn = wave & 1;
    const int rloc = wm * 16 + (lane & 15);
    const int kb16 = (lane >> 4) * 16;   // byte offset of 8-bf16 k-subgroup
    for (int cc = 0; cc < 4; ++cc) {
        f32x4 acc[8];
        #pragma unroll
        for (int f = 0; f < 8; ++f) {
            float bv = b2[cc * 256 + wn * 128 + f * 16 + (lane & 15)];
            acc[f] = (f32x4){ bv, bv, bv, bv };
        }
        #pragma unroll
        for (int ks = 0; ks < 4; ++ks) {
            bf16x8 a = *(const bf16x8*)((const char*)hc + rloc * 256 + HSWZ(rloc, ks * 64 + kb16));
            #pragma unroll
            for (int f = 0; f < 8; ++f) {
                int nT = cc * 16 + wn * 8 + f;
                bf16x8 b = *(const bf16x8*)&W2p[((size_t)(nT * 4 + ks)) * 512 + lane * 8];
                acc[f] = __builtin_amdgcn_mfma_f32_16x16x32_bf16(a, b, acc[f], 0, 0, 0);
            }
        }
        #pragma unroll
        for (int f = 0; f < 8; ++f) {
            int n = cc * 256 + wn * 128 + f * 16 + (lane & 15);
            #pragma unroll
            for (int rr = 0; rr < 4; ++rr) {
                int m = wm * 16 + (lane >> 4) * 4 + rr;
                *(unsigned short*)((char*)h2 + m * 2048 + HSWZ(m, n * 2)) = f2bf(fast_tanh(acc[f][rr]));
            }
        }
    }
    __syncthreads();

    // ---- layers 3+4: layer3 via 32x32x16 (2x4 wave grid), layer4 K-accumulated ----
    const int wrow = wave >> 2, wcol = wave & 3;
    const int arow = wrow * 32 + (lane & 31);
    const int kb32 = (lane >> 5) * 16;

    f32x4 acc4[4];
    #pragma unroll
    for (int f = 0; f < 4; ++f) {
        float bv = b4[wn * 64 + f * 16 + (lane & 15)];
        acc4[f] = (f32x4){ bv, bv, bv, bv };
    }

    for (int c = 0; c < 8; ++c) {
        float bv3 = b3[c * 128 + wcol * 32 + (lane & 31)];
        f32x16 accA, accB;
        #pragma unroll
        for (int i = 0; i < 16; ++i) { accA[i] = bv3; accB[i] = 0.0f; }
        const unsigned short* w3base = &W3p[((size_t)((c * 4 + wcol) * 64)) * 512 + lane * 8];
        #pragma unroll 4
        for (int kt = 0; kt < 64; kt += 2) {
            bf16x8 a0 = *(const bf16x8*)((const char*)h2 + arow * 2048 + HSWZ(arow, kt * 32 + kb32));
            bf16x8 b0 = *(const bf16x8*)(w3base + (size_t)kt * 512);
            accA = __builtin_amdgcn_mfma_f32_32x32x16_bf16(a0, b0, accA, 0, 0, 0);
            bf16x8 a1 = *(const bf16x8*)((const char*)h2 + arow * 2048 + HSWZ(arow, (kt + 1) * 32 + kb32));
            bf16x8 b1 = *(const bf16x8*)(w3base + (size_t)(kt + 1) * 512);
            accB = __builtin_amdgcn_mfma_f32_32x32x16_bf16(a1, b1, accB, 0, 0, 0);
        }
        __syncthreads();   // prior chunk's layer4 reads of hc finished
        #pragma unroll
        for (int r = 0; r < 16; ++r) {
            int row = wrow * 32 + (r & 3) + 8 * (r >> 2) + 4 * (lane >> 5);
            int col = wcol * 32 + (lane & 31);
            *(unsigned short*)((char*)hc + row * 256 + HSWZ(row, col * 2)) =
                f2bf(fast_tanh(accA[r] + accB[r]));
        }
        __syncthreads();   // hc chunk ready
        #pragma unroll
        for (int ks = 0; ks < 4; ++ks) {
            bf16x8 a = *(const bf16x8*)((const char*)hc + rloc * 256 + HSWZ(rloc, ks * 64 + kb16));
            #pragma unroll
            for (int f = 0; f < 4; ++f) {
                int nT = wn * 4 + f;
                bf16x8 b = *(const bf16x8*)&W4p[((size_t)(nT * 32 + c * 4 + ks)) * 512 + lane * 8];
                acc4[f] = __builtin_amdgcn_mfma_f32_16x16x32_bf16(a, b, acc4[f], 0, 0, 0);
            }
        }
    }
    __syncthreads();

    // ---- h4 -> hc ----
    #pragma unroll
    for (int f = 0; f < 4; ++f) {
        int nl = wn * 64 + f * 16 + (lane & 15);
        #pragma unroll
        for (int rr = 0; rr < 4; ++rr) {
            int m = wm * 16 + (lane >> 4) * 4 + rr;
            *(unsigned short*)((char*)hc + m * 256 + HSWZ(m, nl * 2)) = f2bf(fast_tanh(acc4[f][rr]));
        }
    }
    __syncthreads();

    // ---- layer 5 ----
    {
        int r = t >> 3, g = t & 7;
        float part = 0.0f;
        #pragma unroll
        for (int j = 0; j < 16; ++j) {
            int cidx = g * 16 + j;
            unsigned short hb = *(const unsigned short*)((const char*)hc + r * 256 + HSWZ(r, cidx * 2));
            part += bf2f(hb) * W5[cidx];
        }
        part += __shfl_down(part, 4);
        part += __shfl_down(part, 2);
        part += __shfl_down(part, 1);
        if (g == 0) values[p0 + r] = part + b5[0];
    }
}

// ---------------- worklist init / scan / exact evaluator ----------------
__global__ void wl_init(unsigned* wl_cnt) {
    if (threadIdx.x == 0 && blockIdx.x == 0) *wl_cnt = 0u;
}

__global__ __launch_bounds__(256) void scan_argmax(
    const float* __restrict__ values, const float* __restrict__ actions,
    float* __restrict__ out_actions, unsigned* __restrict__ wl_cnt,
    WLE* __restrict__ wl)
{
    int wave = threadIdx.x >> 6, lane = threadIdx.x & 63;
    int s = blockIdx.x * 4 + wave;
    float myv = values[s * 64 + lane];
    float v = myv; int idx = lane;
    #pragma unroll
    for (int off = 32; off; off >>= 1) {
        float ov = __shfl_down(v, off);
        int oi = __shfl_down(idx, off);
        if (ov > v || (ov == v && oi < idx)) { v = ov; idx = oi; }
    }
    float vm = __shfl(v, 0);
    int best = __shfl(idx, 0);
    unsigned long long mask = __ballot(myv >= vm - DELTA);
    if (lane == 0 && __popcll(mask) > 1) {
        unsigned slot = atomicAdd(wl_cnt, 1u);
        if (slot < WL_CAP) { wl[slot].mask = mask; wl[slot].s = (unsigned)s; }
    }
    if (lane < 4) out_actions[s * 4 + lane] = actions[best * 4 + lane];
}

__global__ __launch_bounds__(256) void fixup_eval(
    const float* __restrict__ x, const float* __restrict__ actions,
    const float* __restrict__ W1, const float* __restrict__ b1,
    const float* __restrict__ W2, const float* __restrict__ b2,
    const float* __restrict__ W3, const float* __restrict__ b3,
    const float* __restrict__ W4, const float* __restrict__ b4,
    const float* __restrict__ W5, const float* __restrict__ b5,
    const unsigned* __restrict__ wl_cnt, const WLE* __restrict__ wl,
    float* __restrict__ out_actions)
{
    __shared__ float h1s[8][128];
    __shared__ float h2s[8][1024];
    __shared__ float h3s[8][1024];
    __shared__ float h4s[8][128];
    __shared__ float ain[8][4];
    __shared__ float xs[5];
    __shared__ int cand[64];
    __shared__ int ncand;
    __shared__ float vals[8];
    __shared__ float bestv; __shared__ int besti;

    const int t = threadIdx.x;
    const int n = (int)*wl_cnt;
    for (int e = blockIdx.x; e < n; e += gridDim.x) {
        unsigned long long mask = wl[e].mask;
        int s = (int)wl[e].s;
        if (t == 0) {
            int nn = 0; unsigned long long m2 = mask;
            while (m2) { cand[nn++] = __ffsll(m2) - 1; m2 &= m2 - 1; }
            ncand = nn; bestv = -1e30f; besti = 0;
        }
        if (t < 5) xs[t] = x[s * 5 + t];
        __syncthreads();
        const int NC = ncand;
        for (int g = 0; g < NC; g += 8) {
            if (t < 32) {
                int rr = t >> 2;
                int src = (g + rr < NC) ? cand[g + rr] : cand[g];
                ain[rr][t & 3] = actions[src * 4 + (t & 3)];
            }
            __syncthreads();
            // L1: 9 -> 128
            {
                int r = t >> 5, cb = (t & 31) * 4;
                #pragma unroll
                for (int j = 0; j < 4; ++j) {
                    int c = cb + j;
                    float acc = b1[c];
                    #pragma unroll
                    for (int k = 0; k < 5; ++k) acc += xs[k] * W1[k * 128 + c];
                    #pragma unroll
                    for (int k = 0; k < 4; ++k) acc += ain[r][k] * W1[(5 + k) * 128 + c];
                    h1s[r][c] = tanhf(acc);
                }
            }
            __syncthreads();
            // L2: 128 -> 1024, 8 rows batched
            {
                int cb = t * 4;
                float acc[8][4];
                float4 bv = *(const float4*)&b2[cb];
                #pragma unroll
                for (int r = 0; r < 8; ++r) { acc[r][0]=bv.x; acc[r][1]=bv.y; acc[r][2]=bv.z; acc[r][3]=bv.w; }
                for (int k = 0; k < 128; ++k) {
                    float4 w = *(const float4*)&W2[k * 1024 + cb];
                    #pragma unroll
                    for (int r = 0; r < 8; ++r) {
                        float hv = h1s[r][k];
                        acc[r][0] += hv * w.x; acc[r][1] += hv * w.y;
                        acc[r][2] += hv * w.z; acc[r][3] += hv * w.w;
                    }
                }
                #pragma unroll
                for (int r = 0; r < 8; ++r) {
                    h2s[r][cb+0] = tanhf(acc[r][0]); h2s[r][cb+1] = tanhf(acc[r][1]);
                    h2s[r][cb+2] = tanhf(acc[r][2]); h2s[r][cb+3] = tanhf(acc[r][3]);
                }
            }
            __syncthreads();
            // L3: 1024 -> 1024
            {
                int cb = t * 4;
                float acc[8][4];
                float4 bv = *(const float4*)&b3[cb];
                #pragma unroll
                for (int r = 0; r < 8; ++r) { acc[r][0]=bv.x; acc[r][1]=bv.y; acc[r][2]=bv.z; acc[r][3]=bv.w; }
                for (int k = 0; k < 1024; ++k) {
                    float4 w = *(const float4*)&W3[k * 1024 + cb];
                    #pragma unroll
                    for (int r = 0; r < 8; ++r) {
                        float hv = h2s[r][k];
                        acc[r][0] += hv * w.x; acc[r][1] += hv * w.y;
                        acc[r][2] += hv * w.z; acc[r][3] += hv * w.w;
                    }
                }
                #pragma unroll
                for (int r = 0; r < 8; ++r) {
                    h3s[r][cb+0] = tanhf(acc[r][0]); h3s[r][cb+1] = tanhf(acc[r][1]);
                    h3s[r][cb+2] = tanhf(acc[r][2]); h3s[r][cb+3] = tanhf(acc[r][3]);
                }
            }
            __syncthreads();
            // L4: 1024 -> 128
            {
                int r = t >> 5, cb = (t & 31) * 4;
                float acc[4];
                float4 bv = *(const float4*)&b4[cb];
                acc[0]=bv.x; acc[1]=bv.y; acc[2]=bv.z; acc[3]=bv.w;
                for (int k = 0; k < 1024; ++k) {
                    float4 w = *(const float4*)&W4[k * 128 + cb];
                    float hv = h3s[r][k];
                    acc[0] += hv * w.x; acc[1] += hv * w.y; acc[2] += hv * w.z; acc[3] += hv * w.w;
                }
                h4s[r][cb+0] = tanhf(acc[0]); h4s[r][cb+1] = tanhf(acc[1]);
                h4s[r][cb+2] = tanhf(acc[2]); h4s[r][cb+3] = tanhf(acc[3]);
            }
            __syncthreads();
            // L5 + group argmax (ascending candidate order => first-max)
            if (t < 8) {
                float acc = b5[0];
                for (int k = 0; k < 128; ++k) acc += h4s[t][k] * W5[k];
                vals[t] = acc;
            }
            __syncthreads();
            if (t == 0) {
                int lim = (NC - g < 8) ? (NC - g) : 8;
                for (int i = 0; i < lim; ++i)
                    if (vals[i] > bestv) { bestv = vals[i]; besti = cand[g + i]; }
            }
            __syncthreads();
        }
        if (t < 4) out_actions[s * 4 + t] = actions[besti * 4 + t];
        __syncthreads();
    }
}

// ---------------- fp32 fallback (ws too small) ----------------
#define TR 16
__global__ __launch_bounds__(256) void qnet_fused(
    const float* __restrict__ x, const float* __restrict__ actions,
    const float* __restrict__ W1, const float* __restrict__ b1,
    const float* __restrict__ W2, const float* __restrict__ b2,
    const float* __restrict__ W3, const float* __restrict__ b3,
    const float* __restrict__ W4, const float* __restrict__ b4,
    const float* __restrict__ W5, const float* __restrict__ b5,
    float* __restrict__ values)
{
    __shared__ float h_small[TR][128];
    __shared__ float hA[TR][1024];
    __shared__ float hB[TR][1024];
    const int t = threadIdx.x;
    const int p0 = blockIdx.x * TR;
    for (int i = t; i < TR * 128; i += 256) {
        int r = i >> 7, c = i & 127;
        int p = p0 + r;
        int bidx = p >> 6, aidx = p & 63;
        float acc = b1[c];
        for (int k = 0; k < 5; ++k) acc += x[bidx * 5 + k] * W1[k * 128 + c];
        for (int k = 0; k < 4; ++k) acc += actions[aidx * 4 + k] * W1[(5 + k) * 128 + c];
        h_small[r][c] = tanhf(acc);
    }
    __syncthreads();
    {
        const int c0 = t * 4;
        float4 bias = *(const float4*)&b2[c0];
        float acc[TR][4];
        for (int r = 0; r < TR; ++r) { acc[r][0]=bias.x; acc[r][1]=bias.y; acc[r][2]=bias.z; acc[r][3]=bias.w; }
        for (int k = 0; k < 128; k += 4) {
            float4 w0 = *(const float4*)&W2[(k+0)*1024+c0];
            float4 w1 = *(const float4*)&W2[(k+1)*1024+c0];
            float4 w2 = *(const float4*)&W2[(k+2)*1024+c0];
            float4 w3 = *(const float4*)&W2[(k+3)*1024+c0];
            for (int r = 0; r < TR; ++r) {
                float4 hv = *(const float4*)&h_small[r][k];
                acc[r][0] += hv.x*w0.x + hv.y*w1.x + hv.z*w2.x + hv.w*w3.x;
                acc[r][1] += hv.x*w0.y + hv.y*w1.y + hv.z*w2.y + hv.w*w3.y;
                acc[r][2] += hv.x*w0.z + hv.y*w1.z + hv.z*w2.z + hv.w*w3.z;
                acc[r][3] += hv.x*w0.w + hv.y*w1.w + hv.z*w2.w + hv.w*w3.w;
            }
        }
        for (int r = 0; r < TR; ++r) {
            hA[r][c0+0]=tanhf(acc[r][0]); hA[r][c0+1]=tanhf(acc[r][1]);
            hA[r][c0+2]=tanhf(acc[r][2]); hA[r][c0+3]=tanhf(acc[r][3]);
        }
    }
    __syncthreads();
    {
        const int c0 = t * 4;
        float4 bias = *(const float4*)&b3[c0];
        float acc[TR][4];
        for (int r = 0; r < TR; ++r) { acc[r][0]=bias.x; acc[r][1]=bias.y; acc[r][2]=bias.z; acc[r][3]=bias.w; }
        for (int k = 0; k < 1024; k += 4) {
            float4 w0 = *(const float4*)&W3[(k+0)*1024+c0];
            float4 w1 = *(const float4*)&W3[(k+1)*1024+c0];
            float4 w2 = *(const float4*)&W3[(k+2)*1024+c0];
            float4 w3 = *(const float4*)&W3[(k+3)*1024+c0];
            for (int r = 0; r < TR; ++r) {
                float4 hv = *(const float4*)&hA[r][k];
                acc[r][0] += hv.x*w0.x + hv.y*w1.x + hv.z*w2.x + hv.w*w3.x;
                acc[r][1] += hv.x*w0.y + hv.y*w1.y + hv.z*w2.y + hv.w*w3.y;
                acc[r][2] += hv.x*w0.z + hv.y*w1.z + hv.z*w2.z + hv.w*w3.z;
                acc[r][3] += hv.x*w0.w + hv.y*w1.w + hv.z*w2.w + hv.w*w3.w;
            }
        }
        for (int r = 0; r < TR; ++r) {
            hB[r][c0+0]=tanhf(acc[r][0]); hB[r][c0+1]=tanhf(acc[r][1]);
            hB[r][c0+2]=tanhf(acc[r][2]); hB[r][c0+3]=tanhf(acc[r][3]);
        }
    }
    __syncthreads();
    {
        const int c = t & 127;
        const int rh = t >> 7;
        float acc[8];
        float bias = b4[c];
        for (int r = 0; r < 8; ++r) acc[r] = bias;
        for (int k = 0; k < 1024; k += 4) {
            float w0 = W4[(k+0)*128+c], w1 = W4[(k+1)*128+c];
            float w2 = W4[(k+2)*128+c], w3 = W4[(k+3)*128+c];
            for (int r = 0; r < 8; ++r) {
                float4 hv = *(const float4*)&hB[rh*8+r][k];
                acc[r] += hv.x*w0 + hv.y*w1 + hv.z*w2 + hv.w*w3;
            }
        }
        for (int r = 0; r < 8; ++r) h_small[rh*8+r][c] = tanhf(acc[r]);
    }
    __syncthreads();
    if (t < TR) {
        float acc = b5[0];
        for (int k = 0; k < 128; k += 4) {
            float4 hv = *(const float4*)&h_small[t][k];
            float4 wv = *(const float4*)&W5[k];
            acc += hv.x*wv.x + hv.y*wv.y + hv.z*wv.z + hv.w*wv.w;
        }
        values[p0 + t] = acc;
    }
}

__global__ __launch_bounds__(256) void argmax_gather(
    const float* __restrict__ values, const float* __restrict__ actions,
    float* __restrict__ out_actions)
{
    const int wave = threadIdx.x >> 6;
    const int lane = threadIdx.x & 63;
    const int state = blockIdx.x * (blockDim.x >> 6) + wave;
    float v = values[state * 64 + lane];
    int idx = lane;
    for (int off = 32; off; off >>= 1) {
        float ov = __shfl_down(v, off);
        int oi = __shfl_down(idx, off);
        if (ov > v || (ov == v && oi < idx)) { v = ov; idx = oi; }
    }
    idx = __shfl(idx, 0);
    if (lane < 4) out_actions[state * 4 + lane] = actions[idx * 4 + lane];
}

// ---------------- launcher ----------------
extern "C" void kernel_launch(void* const* d_in, const int* in_sizes, int n_in,
                              void* d_out, int out_size, void* d_ws, size_t ws_size,
                              hipStream_t stream) {
    const float* x       = (const float*)d_in[0];
    const float* actions = (const float*)d_in[1];
    const float* W1 = (const float*)d_in[2];  const float* b1 = (const float*)d_in[3];
    const float* W2 = (const float*)d_in[4];  const float* b2 = (const float*)d_in[5];
    const float* W3 = (const float*)d_in[6];  const float* b3 = (const float*)d_in[7];
    const float* W4 = (const float*)d_in[8];  const float* b4 = (const float*)d_in[9];
    const float* W5 = (const float*)d_in[10]; const float* b5 = (const float*)d_in[11];

    float* out_actions = (float*)d_out;              // [2048,4]
    float* values      = (float*)d_out + 2048 * 4;   // [2048,64]

    const size_t nW2 = 128 * 1024, nW3 = 1024 * 1024, nW4 = 1024 * 128;
    const size_t wbytes = (nW2 + nW3 + nW4) * sizeof(unsigned short);  // 2621440
    const size_t need = wbytes + 16 + (size_t)WL_CAP * sizeof(WLE);

    if (ws_size >= need) {
        unsigned short* W2p = (unsigned short*)d_ws;
        unsigned short* W3p = W2p + nW2;
        unsigned short* W4p = W3p + nW3;
        unsigned* wl_cnt = (unsigned*)((char*)d_ws + wbytes);
        WLE* wl = (WLE*)((char*)d_ws + wbytes + 16);

        pack_w16<<<(int)((nW2 + 255) / 256), 256, 0, stream>>>(W2, W2p, 128, 1024);
        pack_w32<<<(int)((nW3 + 255) / 256), 256, 0, stream>>>(W3, W3p, 1024, 1024);
        pack_w16<<<(int)((nW4 + 255) / 256), 256, 0, stream>>>(W4, W4p, 1024, 128);
        wl_init<<<1, 64, 0, stream>>>(wl_cnt);
        qnet_mfma<<<2048, 512, 0, stream>>>(x, actions, W1, b1, b2, b3, b4, W5, b5,
                                            W2p, W3p, W4p, values);
        scan_argmax<<<512, 256, 0, stream>>>(values, actions, out_actions, wl_cnt, wl);
        fixup_eval<<<512, 256, 0, stream>>>(x, actions, W1, b1, W2, b2, W3, b3,
                                            W4, b4, W5, b5, wl_cnt, wl, out_actions);
    } else {
        qnet_fused<<<2048 * 64 / TR, 256, 0, stream>>>(x, actions, W1, b1, W2, b2, W3, b3,
                                                       W4, b4, W5, b5, values);
        argmax_gather<<<2048 / 4, 256, 0, stream>>>(values, actions, out_actions);
    }
}

// Round 4
// 728.008 us; speedup vs baseline: 10.1944x; 1.2840x over previous
//
#include <hip/hip_runtime.h>
#include <math.h>

// ---------------- common helpers ----------------

typedef short bf16x8 __attribute__((ext_vector_type(8)));
typedef float f32x4 __attribute__((ext_vector_type(4)));
typedef float f32x16 __attribute__((ext_vector_type(16)));

__device__ __host__ inline unsigned short f2bf(float f) {
    union { float f; unsigned u; } v; v.f = f;
    unsigned r = v.u + 0x7fff + ((v.u >> 16) & 1);   // round-to-nearest-even
    return (unsigned short)(r >> 16);
}
__device__ inline float bf2f(unsigned short b) {
    union { unsigned u; float f; } v; v.u = ((unsigned)b) << 16;
    return v.f;
}
__device__ inline float fast_tanh(float x) {
    float e = __expf(2.0f * x);
    return 1.0f - 2.0f / (e + 1.0f);
}

#define DELTA 0.035f
#define WL_CAP 4096

struct WLE { unsigned long long mask; unsigned s; unsigned pad; };

// hc rows are 256 B, h2 rows are 2048 B; (row&15)<<4 is bijective within both.
#define HSWZ(row, b) ((b) ^ (((row) & 15) << 4))

// ---------------- weight packing ----------------
// 16x16x32 B-frag: lane l holds col n=(l&15), k=8*(l>>4)+e (HW-verified).
__global__ __launch_bounds__(256) void pack_w16(const float* __restrict__ src,
                                                unsigned short* __restrict__ dst,
                                                int K, int N) {
    int i = blockIdx.x * 256 + threadIdx.x;
    if (i >= K * N) return;
    int k = i / N, n = i % N;
    int blob = (n >> 4) * (K >> 5) + (k >> 5);
    int lane = (n & 15) | (((k >> 3) & 3) << 4);
    int e = k & 7;
    dst[(size_t)blob * 512 + lane * 8 + e] = f2bf(src[i]);
}
// 32x32x16 B-frag: lane l holds col n=(l&31), k=8*(l>>5)+e (HW-verified round 3).
__global__ __launch_bounds__(256) void pack_w32(const float* __restrict__ src,
                                                unsigned short* __restrict__ dst,
                                                int K, int N) {
    int i = blockIdx.x * 256 + threadIdx.x;
    if (i >= K * N) return;
    int k = i / N, n = i % N;
    int blob = (n >> 5) * (K >> 4) + (k >> 4);
    int lane = (n & 31) | (((k >> 3) & 1) << 5);
    int e = k & 7;
    dst[(size_t)blob * 512 + lane * 8 + e] = f2bf(src[i]);
}

// ---------------- main fused MFMA kernel ----------------
// Block = one state (64 rows = 64 actions), 512 threads = 8 waves.
// L2-traffic-minimal tiling: every packed weight blob is read exactly once per block.
__global__ __launch_bounds__(512, 1) void qnet_mfma(
    const float* __restrict__ x, const float* __restrict__ actions,
    const float* __restrict__ W1, const float* __restrict__ b1,
    const float* __restrict__ b2, const float* __restrict__ b3,
    const float* __restrict__ b4,
    const float* __restrict__ W5, const float* __restrict__ b5,
    const unsigned short* __restrict__ W2p,
    const unsigned short* __restrict__ W3p,
    const unsigned short* __restrict__ W4p,
    float* __restrict__ values)
{
    __shared__ unsigned short h2[64 * 1024];  // 128 KB
    __shared__ unsigned short hc[64 * 128];   // 16 KB: h1 -> h3 chunks -> h4

    const int t = threadIdx.x;
    const int lane = t & 63;
    const int wave = t >> 6;       // 0..7
    const int p0 = blockIdx.x * 64;
    const int kb16 = (lane >> 4) * 16;   // 16x16x32 A k-subgroup byte offset
    const int kb32 = (lane >> 5) * 16;   // 32x32x16 A k-subgroup byte offset

    // ---- layer 1: h1 = tanh([x|a] @ W1 + b1) -> hc ----
    {
        int r = t >> 3;              // action index 0..63
        int c0 = (t & 7) * 16;
        const float* xs = &x[blockIdx.x * 5];
        const float* as = &actions[r * 4];
        float in[9] = { xs[0], xs[1], xs[2], xs[3], xs[4], as[0], as[1], as[2], as[3] };
        #pragma unroll 4
        for (int j = 0; j < 16; ++j) {
            int c = c0 + j;
            float acc = b1[c];
            #pragma unroll
            for (int k = 0; k < 9; ++k) acc += in[k] * W1[k * 128 + c];
            *(unsigned short*)((char*)hc + r * 256 + HSWZ(r, c * 2)) = f2bf(fast_tanh(acc));
        }
    }
    __syncthreads();

    // ---- layer 2: 128 -> 1024. Wave owns cols [wave*128, +128), all 4 row-tiles.
    //      A hoisted to regs once; W2 read exactly once per block. ----
    {
        bf16x8 Af[4][4];
        #pragma unroll
        for (int rt = 0; rt < 4; ++rt)
            #pragma unroll
            for (int ks = 0; ks < 4; ++ks) {
                int row = rt * 16 + (lane & 15);
                Af[rt][ks] = *(const bf16x8*)((const char*)hc + row * 256 + HSWZ(row, ks * 64 + kb16));
            }
        #pragma unroll 2
        for (int f = 0; f < 8; ++f) {
            int nT = wave * 8 + f;
            float bv = b2[nT * 16 + (lane & 15)];
            f32x4 acc[4];
            #pragma unroll
            for (int rt = 0; rt < 4; ++rt) acc[rt] = (f32x4){ bv, bv, bv, bv };
            #pragma unroll
            for (int ks = 0; ks < 4; ++ks) {
                bf16x8 b = *(const bf16x8*)&W2p[((size_t)(nT * 4 + ks)) * 512 + lane * 8];
                #pragma unroll
                for (int rt = 0; rt < 4; ++rt)
                    acc[rt] = __builtin_amdgcn_mfma_f32_16x16x32_bf16(Af[rt][ks], b, acc[rt], 0, 0, 0);
            }
            int n = nT * 16 + (lane & 15);
            #pragma unroll
            for (int rt = 0; rt < 4; ++rt)
                #pragma unroll
                for (int rr = 0; rr < 4; ++rr) {
                    int m = rt * 16 + (lane >> 4) * 4 + rr;
                    *(unsigned short*)((char*)h2 + m * 2048 + HSWZ(m, n * 2)) = f2bf(fast_tanh(acc[rt][rr]));
                }
        }
    }
    __syncthreads();

    // ---- layers 3+4: layer3 32x32x16, wave = 2 row-tiles x 2 col-tiles sharing B.
    //      W3 and W4 each read exactly once per block. ----
    const int g4 = wave >> 2;                  // hc-chunk write group
    const float bv4 = b4[wave * 16 + (lane & 15)];
    f32x4 acc4[4];
    #pragma unroll
    for (int rt = 0; rt < 4; ++rt) acc4[rt] = (f32x4){ bv4, bv4, bv4, bv4 };

    for (int sc = 0; sc < 2; ++sc) {
        // compute 4 accumulators: rows {0-31, 32-63} x cols {c0, c0+256}
        int col0 = sc * 512 + wave * 32 + (lane & 31);
        float bv0 = b3[col0], bv1 = b3[col0 + 256];
        f32x16 a00, a01, a10, a11;
        #pragma unroll
        for (int i = 0; i < 16; ++i) { a00[i] = bv0; a10[i] = bv0; a01[i] = bv1; a11[i] = bv1; }

        const int r0 = lane & 31, r1 = 32 + (lane & 31);
        const size_t bb0 = ((size_t)((sc * 16 + wave) * 64)) * 512 + lane * 8;
        #pragma unroll 4
        for (int kt = 0; kt < 64; ++kt) {
            bf16x8 A0 = *(const bf16x8*)((const char*)h2 + r0 * 2048 + HSWZ(r0, kt * 32 + kb32));
            bf16x8 A1 = *(const bf16x8*)((const char*)h2 + r1 * 2048 + HSWZ(r1, kt * 32 + kb32));
            bf16x8 B0 = *(const bf16x8*)&W3p[bb0 + (size_t)kt * 512];
            bf16x8 B1 = *(const bf16x8*)&W3p[bb0 + 262144 + (size_t)kt * 512];
            a00 = __builtin_amdgcn_mfma_f32_32x32x16_bf16(A0, B0, a00, 0, 0, 0);
            a10 = __builtin_amdgcn_mfma_f32_32x32x16_bf16(A1, B0, a10, 0, 0, 0);
            a01 = __builtin_amdgcn_mfma_f32_32x32x16_bf16(A0, B1, a01, 0, 0, 0);
            a11 = __builtin_amdgcn_mfma_f32_32x32x16_bf16(A1, B1, a11, 0, 0, 0);
        }

        // stage h3 into hc in four 128-col chunks; layer4 partial after each
        #pragma unroll
        for (int j = 0; j < 4; ++j) {
            __syncthreads();   // hc free (previous layer4 / layer2-h1 reads done)
            if ((j & 1) == g4) {
                int colL = (wave & 3) * 32 + (lane & 31);
                #pragma unroll
                for (int r = 0; r < 16; ++r) {
                    int rowbase = (r & 3) + 8 * (r >> 2) + 4 * (lane >> 5);
                    float v0 = (j >> 1) ? a01[r] : a00[r];
                    float v1 = (j >> 1) ? a11[r] : a10[r];
                    int row1 = 32 + rowbase;
                    *(unsigned short*)((char*)hc + rowbase * 256 + HSWZ(rowbase, colL * 2)) = f2bf(fast_tanh(v0));
                    *(unsigned short*)((char*)hc + row1 * 256 + HSWZ(row1, colL * 2)) = f2bf(fast_tanh(v1));
                }
            }
            __syncthreads();   // hc chunk ready
            int kchunk = sc * 4 + j;
            #pragma unroll
            for (int ks = 0; ks < 4; ++ks) {
                bf16x8 b = *(const bf16x8*)&W4p[((size_t)(wave * 32 + kchunk * 4 + ks)) * 512 + lane * 8];
                #pragma unroll
                for (int rt = 0; rt < 4; ++rt) {
                    int row = rt * 16 + (lane & 15);
                    bf16x8 a = *(const bf16x8*)((const char*)hc + row * 256 + HSWZ(row, ks * 64 + kb16));
                    acc4[rt] = __builtin_amdgcn_mfma_f32_16x16x32_bf16(a, b, acc4[rt], 0, 0, 0);
                }
            }
        }
    }
    __syncthreads();   // last layer4 hc reads done

    // ---- h4 = tanh(acc4) -> hc ----
    {
        int n = wave * 16 + (lane & 15);
        #pragma unroll
        for (int rt = 0; rt < 4; ++rt)
            #pragma unroll
            for (int rr = 0; rr < 4; ++rr) {
                int m = rt * 16 + (lane >> 4) * 4 + rr;
                *(unsigned short*)((char*)hc + m * 256 + HSWZ(m, n * 2)) = f2bf(fast_tanh(acc4[rt][rr]));
            }
    }
    __syncthreads();

    // ---- layer 5: values = h4 @ W5 + b5 ----
    {
        int r = t >> 3, g = t & 7;
        float part = 0.0f;
        #pragma unroll
        for (int j = 0; j < 16; ++j) {
            int cidx = g * 16 + j;
            unsigned short hb = *(const unsigned short*)((const char*)hc + r * 256 + HSWZ(r, cidx * 2));
            part += bf2f(hb) * W5[cidx];
        }
        part += __shfl_down(part, 4);
        part += __shfl_down(part, 2);
        part += __shfl_down(part, 1);
        if (g == 0) values[p0 + r] = part + b5[0];
    }
}

// ---------------- worklist init / scan / exact evaluator ----------------
__global__ void wl_init(unsigned* wl_cnt) {
    if (threadIdx.x == 0 && blockIdx.x == 0) *wl_cnt = 0u;
}

__global__ __launch_bounds__(256) void scan_argmax(
    const float* __restrict__ values, const float* __restrict__ actions,
    float* __restrict__ out_actions, unsigned* __restrict__ wl_cnt,
    WLE* __restrict__ wl)
{
    int wave = threadIdx.x >> 6, lane = threadIdx.x & 63;
    int s = blockIdx.x * 4 + wave;
    float myv = values[s * 64 + lane];
    float v = myv; int idx = lane;
    #pragma unroll
    for (int off = 32; off; off >>= 1) {
        float ov = __shfl_down(v, off);
        int oi = __shfl_down(idx, off);
        if (ov > v || (ov == v && oi < idx)) { v = ov; idx = oi; }
    }
    float vm = __shfl(v, 0);
    int best = __shfl(idx, 0);
    unsigned long long mask = __ballot(myv >= vm - DELTA);
    if (lane == 0 && __popcll(mask) > 1) {
        unsigned slot = atomicAdd(wl_cnt, 1u);
        if (slot < WL_CAP) { wl[slot].mask = mask; wl[slot].s = (unsigned)s; }
    }
    if (lane < 4) out_actions[s * 4 + lane] = actions[best * 4 + lane];
}

__global__ __launch_bounds__(256) void fixup_eval(
    const float* __restrict__ x, const float* __restrict__ actions,
    const float* __restrict__ W1, const float* __restrict__ b1,
    const float* __restrict__ W2, const float* __restrict__ b2,
    const float* __restrict__ W3, const float* __restrict__ b3,
    const float* __restrict__ W4, const float* __restrict__ b4,
    const float* __restrict__ W5, const float* __restrict__ b5,
    const unsigned* __restrict__ wl_cnt, const WLE* __restrict__ wl,
    float* __restrict__ out_actions)
{
    __shared__ float h1s[8][128];
    __shared__ float h2s[8][1024];
    __shared__ float h3s[8][1024];
    __shared__ float h4s[8][128];
    __shared__ float ain[8][4];
    __shared__ float xs[5];
    __shared__ int cand[64];
    __shared__ int ncand;
    __shared__ float vals[8];
    __shared__ float bestv; __shared__ int besti;

    const int t = threadIdx.x;
    const int n = (int)*wl_cnt;
    for (int e = blockIdx.x; e < n; e += gridDim.x) {
        unsigned long long mask = wl[e].mask;
        int s = (int)wl[e].s;
        if (t == 0) {
            int nn = 0; unsigned long long m2 = mask;
            while (m2) { cand[nn++] = __ffsll(m2) - 1; m2 &= m2 - 1; }
            ncand = nn; bestv = -1e30f; besti = 0;
        }
        if (t < 5) xs[t] = x[s * 5 + t];
        __syncthreads();
        const int NC = ncand;
        for (int g = 0; g < NC; g += 8) {
            if (t < 32) {
                int rr = t >> 2;
                int src = (g + rr < NC) ? cand[g + rr] : cand[g];
                ain[rr][t & 3] = actions[src * 4 + (t & 3)];
            }
            __syncthreads();
            {
                int r = t >> 5, cb = (t & 31) * 4;
                #pragma unroll
                for (int j = 0; j < 4; ++j) {
                    int c = cb + j;
                    float acc = b1[c];
                    #pragma unroll
                    for (int k = 0; k < 5; ++k) acc += xs[k] * W1[k * 128 + c];
                    #pragma unroll
                    for (int k = 0; k < 4; ++k) acc += ain[r][k] * W1[(5 + k) * 128 + c];
                    h1s[r][c] = tanhf(acc);
                }
            }
            __syncthreads();
            {
                int cb = t * 4;
                float acc[8][4];
                float4 bv = *(const float4*)&b2[cb];
                #pragma unroll
                for (int r = 0; r < 8; ++r) { acc[r][0]=bv.x; acc[r][1]=bv.y; acc[r][2]=bv.z; acc[r][3]=bv.w; }
                for (int k = 0; k < 128; ++k) {
                    float4 w = *(const float4*)&W2[k * 1024 + cb];
                    #pragma unroll
                    for (int r = 0; r < 8; ++r) {
                        float hv = h1s[r][k];
                        acc[r][0] += hv * w.x; acc[r][1] += hv * w.y;
                        acc[r][2] += hv * w.z; acc[r][3] += hv * w.w;
                    }
                }
                #pragma unroll
                for (int r = 0; r < 8; ++r) {
                    h2s[r][cb+0] = tanhf(acc[r][0]); h2s[r][cb+1] = tanhf(acc[r][1]);
                    h2s[r][cb+2] = tanhf(acc[r][2]); h2s[r][cb+3] = tanhf(acc[r][3]);
                }
            }
            __syncthreads();
            {
                int cb = t * 4;
                float acc[8][4];
                float4 bv = *(const float4*)&b3[cb];
                #pragma unroll
                for (int r = 0; r < 8; ++r) { acc[r][0]=bv.x; acc[r][1]=bv.y; acc[r][2]=bv.z; acc[r][3]=bv.w; }
                for (int k = 0; k < 1024; ++k) {
                    float4 w = *(const float4*)&W3[k * 1024 + cb];
                    #pragma unroll
                    for (int r = 0; r < 8; ++r) {
                        float hv = h2s[r][k];
                        acc[r][0] += hv * w.x; acc[r][1] += hv * w.y;
                        acc[r][2] += hv * w.z; acc[r][3] += hv * w.w;
                    }
                }
                #pragma unroll
                for (int r = 0; r < 8; ++r) {
                    h3s[r][cb+0] = tanhf(acc[r][0]); h3s[r][cb+1] = tanhf(acc[r][1]);
                    h3s[r][cb+2] = tanhf(acc[r][2]); h3s[r][cb+3] = tanhf(acc[r][3]);
                }
            }
            __syncthreads();
            {
                int r = t >> 5, cb = (t & 31) * 4;
                float acc[4];
                float4 bv = *(const float4*)&b4[cb];
                acc[0]=bv.x; acc[1]=bv.y; acc[2]=bv.z; acc[3]=bv.w;
                for (int k = 0; k < 1024; ++k) {
                    float4 w = *(const float4*)&W4[k * 128 + cb];
                    float hv = h3s[r][k];
                    acc[0] += hv * w.x; acc[1] += hv * w.y; acc[2] += hv * w.z; acc[3] += hv * w.w;
                }
                h4s[r][cb+0] = tanhf(acc[0]); h4s[r][cb+1] = tanhf(acc[1]);
                h4s[r][cb+2] = tanhf(acc[2]); h4s[r][cb+3] = tanhf(acc[3]);
            }
            __syncthreads();
            if (t < 8) {
                float acc = b5[0];
                for (int k = 0; k < 128; ++k) acc += h4s[t][k] * W5[k];
                vals[t] = acc;
            }
            __syncthreads();
            if (t == 0) {
                int lim = (NC - g < 8) ? (NC - g) : 8;
                for (int i = 0; i < lim; ++i)
                    if (vals[i] > bestv) { bestv = vals[i]; besti = cand[g + i]; }
            }
            __syncthreads();
        }
        if (t < 4) out_actions[s * 4 + t] = actions[besti * 4 + t];
        __syncthreads();
    }
}

// ---------------- fp32 fallback (ws too small) ----------------
#define TR 16
__global__ __launch_bounds__(256) void qnet_fused(
    const float* __restrict__ x, const float* __restrict__ actions,
    const float* __restrict__ W1, const float* __restrict__ b1,
    const float* __restrict__ W2, const float* __restrict__ b2,
    const float* __restrict__ W3, const float* __restrict__ b3,
    const float* __restrict__ W4, const float* __restrict__ b4,
    const float* __restrict__ W5, const float* __restrict__ b5,
    float* __restrict__ values)
{
    __shared__ float h_small[TR][128];
    __shared__ float hA[TR][1024];
    __shared__ float hB[TR][1024];
    const int t = threadIdx.x;
    const int p0 = blockIdx.x * TR;
    for (int i = t; i < TR * 128; i += 256) {
        int r = i >> 7, c = i & 127;
        int p = p0 + r;
        int bidx = p >> 6, aidx = p & 63;
        float acc = b1[c];
        for (int k = 0; k < 5; ++k) acc += x[bidx * 5 + k] * W1[k * 128 + c];
        for (int k = 0; k < 4; ++k) acc += actions[aidx * 4 + k] * W1[(5 + k) * 128 + c];
        h_small[r][c] = tanhf(acc);
    }
    __syncthreads();
    {
        const int c0 = t * 4;
        float4 bias = *(const float4*)&b2[c0];
        float acc[TR][4];
        for (int r = 0; r < TR; ++r) { acc[r][0]=bias.x; acc[r][1]=bias.y; acc[r][2]=bias.z; acc[r][3]=bias.w; }
        for (int k = 0; k < 128; k += 4) {
            float4 w0 = *(const float4*)&W2[(k+0)*1024+c0];
            float4 w1 = *(const float4*)&W2[(k+1)*1024+c0];
            float4 w2 = *(const float4*)&W2[(k+2)*1024+c0];
            float4 w3 = *(const float4*)&W2[(k+3)*1024+c0];
            for (int r = 0; r < TR; ++r) {
                float4 hv = *(const float4*)&h_small[r][k];
                acc[r][0] += hv.x*w0.x + hv.y*w1.x + hv.z*w2.x + hv.w*w3.x;
                acc[r][1] += hv.x*w0.y + hv.y*w1.y + hv.z*w2.y + hv.w*w3.y;
                acc[r][2] += hv.x*w0.z + hv.y*w1.z + hv.z*w2.z + hv.w*w3.z;
                acc[r][3] += hv.x*w0.w + hv.y*w1.w + hv.z*w2.w + hv.w*w3.w;
            }
        }
        for (int r = 0; r < TR; ++r) {
            hA[r][c0+0]=tanhf(acc[r][0]); hA[r][c0+1]=tanhf(acc[r][1]);
            hA[r][c0+2]=tanhf(acc[r][2]); hA[r][c0+3]=tanhf(acc[r][3]);
        }
    }
    __syncthreads();
    {
        const int c0 = t * 4;
        float4 bias = *(const float4*)&b3[c0];
        float acc[TR][4];
        for (int r = 0; r < TR; ++r) { acc[r][0]=bias.x; acc[r][1]=bias.y; acc[r][2]=bias.z; acc[r][3]=bias.w; }
        for (int k = 0; k < 1024; k += 4) {
            float4 w0 = *(const float4*)&W3[(k+0)*1024+c0];
            float4 w1 = *(const float4*)&W3[(k+1)*1024+c0];
            float4 w2 = *(const float4*)&W3[(k+2)*1024+c0];
            float4 w3 = *(const float4*)&W3[(k+3)*1024+c0];
            for (int r = 0; r < TR; ++r) {
                float4 hv = *(const float4*)&hA[r][k];
                acc[r][0] += hv.x*w0.x + hv.y*w1.x + hv.z*w2.x + hv.w*w3.x;
                acc[r][1] += hv.x*w0.y + hv.y*w1.y + hv.z*w2.y + hv.w*w3.y;
                acc[r][2] += hv.x*w0.z + hv.y*w1.z + hv.z*w2.z + hv.w*w3.z;
                acc[r][3] += hv.x*w0.w + hv.y*w1.w + hv.z*w2.w + hv.w*w3.w;
            }
        }
        for (int r = 0; r < TR; ++r) {
            hB[r][c0+0]=tanhf(acc[r][0]); hB[r][c0+1]=tanhf(acc[r][1]);
            hB[r][c0+2]=tanhf(acc[r][2]); hB[r][c0+3]=tanhf(acc[r][3]);
        }
    }
    __syncthreads();
    {
        const int c = t & 127;
        const int rh = t >> 7;
        float acc[8];
        float bias = b4[c];
        for (int r = 0; r < 8; ++r) acc[r] = bias;
        for (int k = 0; k < 1024; k += 4) {
            float w0 = W4[(k+0)*128+c], w1 = W4[(k+1)*128+c];
            float w2 = W4[(k+2)*128+c], w3 = W4[(k+3)*128+c];
            for (int r = 0; r < 8; ++r) {
                float4 hv = *(const float4*)&hB[rh*8+r][k];
                acc[r] += hv.x*w0 + hv.y*w1 + hv.z*w2 + hv.w*w3;
            }
        }
        for (int r = 0; r < 8; ++r) h_small[rh*8+r][c] = tanhf(acc[r]);
    }
    __syncthreads();
    if (t < TR) {
        float acc = b5[0];
        for (int k = 0; k < 128; k += 4) {
            float4 hv = *(const float4*)&h_small[t][k];
            float4 wv = *(const float4*)&W5[k];
            acc += hv.x*wv.x + hv.y*wv.y + hv.z*wv.z + hv.w*wv.w;
        }
        values[p0 + t] = acc;
    }
}

__global__ __launch_bounds__(256) void argmax_gather(
    const float* __restrict__ values, const float* __restrict__ actions,
    float* __restrict__ out_actions)
{
    const int wave = threadIdx.x >> 6;
    const int lane = threadIdx.x & 63;
    const int state = blockIdx.x * (blockDim.x >> 6) + wave;
    float v = values[state * 64 + lane];
    int idx = lane;
    for (int off = 32; off; off >>= 1) {
        float ov = __shfl_down(v, off);
        int oi = __shfl_down(idx, off);
        if (ov > v || (ov == v && oi < idx)) { v = ov; idx = oi; }
    }
    idx = __shfl(idx, 0);
    if (lane < 4) out_actions[state * 4 + lane] = actions[idx * 4 + lane];
}

// ---------------- launcher ----------------
extern "C" void kernel_launch(void* const* d_in, const int* in_sizes, int n_in,
                              void* d_out, int out_size, void* d_ws, size_t ws_size,
                              hipStream_t stream) {
    const float* x       = (const float*)d_in[0];
    const float* actions = (const float*)d_in[1];
    const float* W1 = (const float*)d_in[2];  const float* b1 = (const float*)d_in[3];
    const float* W2 = (const float*)d_in[4];  const float* b2 = (const float*)d_in[5];
    const float* W3 = (const float*)d_in[6];  const float* b3 = (const float*)d_in[7];
    const float* W4 = (const float*)d_in[8];  const float* b4 = (const float*)d_in[9];
    const float* W5 = (const float*)d_in[10]; const float* b5 = (const float*)d_in[11];

    float* out_actions = (float*)d_out;              // [2048,4]
    float* values      = (float*)d_out + 2048 * 4;   // [2048,64]

    const size_t nW2 = 128 * 1024, nW3 = 1024 * 1024, nW4 = 1024 * 128;
    const size_t wbytes = (nW2 + nW3 + nW4) * sizeof(unsigned short);
    const size_t need = wbytes + 16 + (size_t)WL_CAP * sizeof(WLE);

    if (ws_size >= need) {
        unsigned short* W2p = (unsigned short*)d_ws;
        unsigned short* W3p = W2p + nW2;
        unsigned short* W4p = W3p + nW3;
        unsigned* wl_cnt = (unsigned*)((char*)d_ws + wbytes);
        WLE* wl = (WLE*)((char*)d_ws + wbytes + 16);

        pack_w16<<<(int)((nW2 + 255) / 256), 256, 0, stream>>>(W2, W2p, 128, 1024);
        pack_w32<<<(int)((nW3 + 255) / 256), 256, 0, stream>>>(W3, W3p, 1024, 1024);
        pack_w16<<<(int)((nW4 + 255) / 256), 256, 0, stream>>>(W4, W4p, 1024, 128);
        wl_init<<<1, 64, 0, stream>>>(wl_cnt);
        qnet_mfma<<<2048, 512, 0, stream>>>(x, actions, W1, b1, b2, b3, b4, W5, b5,
                                            W2p, W3p, W4p, values);
        scan_argmax<<<512, 256, 0, stream>>>(values, actions, out_actions, wl_cnt, wl);
        fixup_eval<<<512, 256, 0, stream>>>(x, actions, W1, b1, W2, b2, W3, b3,
                                            W4, b4, W5, b5, wl_cnt, wl, out_actions);
    } else {
        qnet_fused<<<2048 * 64 / TR, 256, 0, stream>>>(x, actions, W1, b1, W2, b2, W3, b3,
                                                       W4, b4, W5, b5, values);
        argmax_gather<<<2048 / 4, 256, 0, stream>>>(values, actions, out_actions);
    }
}